// Round 12
// baseline (356.124 us; speedup 1.0000x reference)
//
#include <hip/hip_runtime.h>
#include <math.h>

#define LOG2PI_F 1.8378770664093453f

// ws layout (floats)
#define WS_Q    0                       // 512
#define WS_SCAL 512                     // 32: [0]=step1 [1]=step2 [2]=logdet_LI [3..11]=w1_inv [12..20]=w2_inv
#define WS_M    544                     // 512*512 (L + I, consumed by big chol)
#define WS_CHR  (544 + 512*512)         // 500*64*3 = 96000
#define WS_S34  (WS_CHR + 96000)        // 16000
#define WS_FLG  (WS_S34 + 16000)        // 16 arrival flags, one per 128B line (16 x 32 ints)
#define WS_FIN  (WS_FLG + 512)          // small-block completion counter, own 128B line

#define CHOL_BLOCKS 16
#define SMALL_BLOCKS 2000

__device__ inline void inv3(const float* w, float* out){
  float a=w[0],b=w[1],c=w[2],d=w[3],e=w[4],f=w[5],g=w[6],h=w[7],i=w[8];
  float A = e*i - f*h;
  float B = -(d*i - f*g);
  float C = d*h - e*g;
  float det = a*A + b*B + c*C;
  float id = 1.0f/det;
  out[0]=A*id;            out[1]=-(b*i - c*h)*id; out[2]=(b*f - c*e)*id;
  out[3]=B*id;            out[4]=(a*i - c*g)*id;  out[5]=-(a*f - c*d)*id;
  out[6]=C*id;            out[7]=-(a*h - b*g)*id; out[8]=(a*e - b*d)*id;
}

// wave-local LDS ordering: a CDNA wave is lockstep, so draining the LDS queue
// is a sufficient barrier between lanes of the SAME wave.
__device__ inline void wave_lds_sync(){
  asm volatile("s_waitcnt lgkmcnt(0)" ::: "memory");
}

// broadcast lane l's value via SALU readlane (l compile-time constant in
// unrolled loops). ONLY on dependent pivot chains (latency-bound); the
// throughput-bound broadcast inner loops use LDS broadcast reads (R5 lesson).
__device__ inline float rdlane(float v, int l){
  return __int_as_float(__builtin_amdgcn_readlane(__float_as_int(v), l));
}

// Parallel arrival-flag device barrier (R11, measured ≈ R4's atomic gbar):
// each block release-stores its own flag line; wave 0 polls all 16 with one
// vector load + __all. Monotonic base+round targets -> replay-robust.
__device__ inline void gbarf(float* ws, int cb, int target){
  __syncthreads();
  int* flags = (int*)(ws + WS_FLG);
  if (threadIdx.x == 0){
    __hip_atomic_store(&flags[cb*32], target, __ATOMIC_RELEASE, __HIP_MEMORY_SCOPE_AGENT);
  }
  if (threadIdx.x < 64){
    const int idx = (int)threadIdx.x & 15;      // 4 lanes per flag line
    for (;;){
      int v = __hip_atomic_load(&flags[idx*32], __ATOMIC_RELAXED, __HIP_MEMORY_SCOPE_AGENT);
      if (__all(v >= target)) break;
      __builtin_amdgcn_s_sleep(1);
    }
  }
  if (threadIdx.x == 0){
    (void)__hip_atomic_load(&flags[cb*32], __ATOMIC_ACQUIRE, __HIP_MEMORY_SCOPE_AGENT);
  }
  __syncthreads();
}

// ---------------- prep: q, step1, step2, 3x3 inverses, flag+counter init ----------------
__global__ __launch_bounds__(512) void k_prep(const float* __restrict__ mus,
    const float* __restrict__ fkw1, const float* __restrict__ fkb1,
    const float* __restrict__ fkw2, const float* __restrict__ fkb2,
    const float* __restrict__ dfw1, const float* __restrict__ dfw2,
    float* ws){
  int t = threadIdx.x;          // 0..511 == N
  __shared__ float red[512];
  float m0 = mus[t*3+0], m1 = mus[t*3+1], m2 = mus[t*3+2];
  float h0 = tanhf(fkw1[0]*m0 + fkw1[1]*m1 + fkw1[2]*m2 + fkb1[0]);
  float h1 = tanhf(fkw1[3]*m0 + fkw1[4]*m1 + fkw1[5]*m2 + fkb1[1]);
  float h2 = tanhf(fkw1[6]*m0 + fkw1[7]*m1 + fkw1[8]*m2 + fkb1[2]);
  float logq = fkw2[0]*h0 + fkw2[1]*h1 + fkw2[2]*h2 + fkb2[0];
  ws[WS_Q + t] = expf(logq);
  ((int*)(ws + WS_FLG))[t] = 0;          // zero the 512-int flag region
  red[t] = -0.5f*(m0*m0 + m1*m1 + m2*m2);
  __syncthreads();
  for (int s = 256; s; s >>= 1){ if (t < s) red[t] += red[t+s]; __syncthreads(); }
  if (t == 0){
    ws[WS_SCAL+1] = red[0] - 512.0f*1.5f*LOG2PI_F;                       // step2
    ws[WS_SCAL+0] = 512.0f*logf(500.0f) - 500.0f - lgammaf(513.0f);      // step1
    inv3(dfw1, ws + WS_SCAL + 3);
    inv3(dfw2, ws + WS_SCAL + 12);
    ((int*)(ws + WS_FIN))[0] = 0;        // small-completion counter
  }
}

// ---------------- fused chromes (blocks 0..124) + build M = L+I (blocks 125..1148) ----------------
__global__ __launch_bounds__(256) void k_cl(const float* __restrict__ colors,
    const float* __restrict__ dfb1, const float* __restrict__ dfb2,
    const float* __restrict__ mus, float* ws){
  const int b = blockIdx.x;
  if (b < 125){
    int id = b*256 + threadIdx.x;                 // < 32000 exact
    const float* w1i = ws + WS_SCAL + 3;
    const float* w2i = ws + WS_SCAL + 12;
    float c0 = colors[id*3+0] - dfb2[0];
    float c1 = colors[id*3+1] - dfb2[1];
    float c2 = colors[id*3+2] - dfb2[2];
    float z0 = w2i[0]*c0 + w2i[1]*c1 + w2i[2]*c2;
    float z1 = w2i[3]*c0 + w2i[4]*c1 + w2i[5]*c2;
    float z2 = w2i[6]*c0 + w2i[7]*c1 + w2i[8]*c2;
    const float lo = -1.0f + 1e-6f, hi = 1.0f - 1e-6f;
    z0 = atanhf(fminf(fmaxf(z0, lo), hi)) - dfb1[0];
    z1 = atanhf(fminf(fmaxf(z1, lo), hi)) - dfb1[1];
    z2 = atanhf(fminf(fmaxf(z2, lo), hi)) - dfb1[2];
    ws[WS_CHR + id*3+0] = w1i[0]*z0 + w1i[1]*z1 + w1i[2]*z2;
    ws[WS_CHR + id*3+1] = w1i[3]*z0 + w1i[4]*z1 + w1i[5]*z2;
    ws[WS_CHR + id*3+2] = w1i[6]*z0 + w1i[7]*z1 + w1i[8]*z2;
  } else {
    int id = (b - 125)*256 + threadIdx.x;         // < 262144 exact
    int i = id >> 9, j = id & 511;
    float dx = mus[i*3+0]-mus[j*3+0];
    float dy = mus[i*3+1]-mus[j*3+1];
    float dz = mus[i*3+2]-mus[j*3+2];
    float d2 = dx*dx + dy*dy + dz*dz;
    float v = ws[WS_Q+i]*ws[WS_Q+j]*expf(-0.5f*d2);
    if (i == j) v += 1.0f;
    ws[WS_M + id] = v;
  }
}

// ---------------- fused: blocks 0..15 = cooperative big Cholesky (R11 panel loop);
// blocks 16..2015 = 8 small 64x64 logdets each; chol block 0 runs the finale
// after polling the small-completion counter (fire-and-forget increments) ----------------
__global__ __launch_bounds__(512) void k_fused(const int* __restrict__ align,
    const float* __restrict__ mus, float* ws, float* __restrict__ out){
  __shared__ __align__(16) float smem[16384];     // 64 KiB, overlaid by both paths + finale

  if (blockIdx.x < CHOL_BLOCKS){
    // -------- big Cholesky on 16 workgroups (panel factor redundant, SYRK split 32 ways) --------
    __builtin_amdgcn_s_setprio(1);
    const int cb = blockIdx.x;
    float* M = ws + WS_M;
    float (*PnT)[512] = reinterpret_cast<float (*)[512]>(smem);   // [32][512]
    const int t = threadIdx.x;
    float lgacc = 0.f;
    // replay-robust barrier base: own flag's stale value (all flags equal at entry)
    const int base = __hip_atomic_load((int*)(ws + WS_FLG) + cb*32,
                                       __ATOMIC_RELAXED, __HIP_MEMORY_SCOPE_AGENT);

    for (int p = 0; p < 16; ++p){
      const int k0 = p << 5;
      const int H = 512 - k0;
      // stage panel cols [k0,k0+32) rows [k0,512) transposed into LDS
      if (t < H){
        const int r = k0 + t;
        #pragma unroll
        for (int c4 = 0; c4 < 8; ++c4){
          float4 v = *(const float4*)&M[r*512 + k0 + c4*4];
          PnT[c4*4+0][r] = v.x;
          PnT[c4*4+1][r] = v.y;
          PnT[c4*4+2][r] = v.z;
          PnT[c4*4+3][r] = v.w;
        }
      }
      __syncthreads();
      // diag-block Cholesky on wave 0 (lanes 0..31): SALU readlane broadcast
      if (t < 32){
        float x[32];
        #pragma unroll
        for (int c = 0; c < 32; ++c) x[c] = PnT[c][k0 + t];
        float invd = 1.f, mydiag = 1.f;
        #pragma unroll
        for (int c = 0; c < 32; ++c){
          float piv = rdlane(x[c], c);
          float sq = sqrtf(fmaxf(piv, 1e-30f));
          float inv = 1.0f / sq;
          float xc = x[c] * inv;
          if (t == c){ xc = sq; invd = inv; mydiag = sq; }
          x[c] = xc;
          #pragma unroll
          for (int j = c + 1; j < 32; ++j){
            float cj = rdlane(x[c], j);     // lane j's scaled column entry
            x[j] -= x[c] * cj;
          }
        }
        // write factor back transposed: zeros above diag, 1/Lcc on diag slot
        #pragma unroll
        for (int c = 0; c < 32; ++c){
          float val = (t > c) ? x[c] : ((t == c) ? invd : 0.f);
          PnT[c][k0 + t] = val;
        }
        float lg = logf(mydiag);
        #pragma unroll
        for (int off = 16; off; off >>= 1) lg += __shfl_down(lg, off);
        if (t == 0) lgacc += lg;
      }
      __syncthreads();
      // trsm (8 waves, one row/thread; R10 lesson: fewer waves exposes latency)
      {
        const int r = k0 + 32 + t;
        if (r < 512){
          float y[32];
          #pragma unroll
          for (int c = 0; c < 32; ++c) y[c] = PnT[c][r];
          #pragma unroll
          for (int c = 0; c < 32; ++c){
            const float inv = PnT[c][k0 + c];    // 1/Lcc
            const float yc = y[c] * inv;
            #pragma unroll
            for (int q4 = c >> 2; q4 < 8; ++q4){
              float4 f = *(const float4*)&PnT[c][k0 + q4*4];
              y[q4*4+0] -= yc * f.x;
              y[q4*4+1] -= yc * f.y;
              y[q4*4+2] -= yc * f.z;
              y[q4*4+3] -= yc * f.w;
            }
            y[c] = yc;   // fix slot clobbered by the diag-quad update
          }
          #pragma unroll
          for (int c = 0; c < 32; ++c) PnT[c][r] = y[c];
        }
      }
      __syncthreads();
      // trailing SYRK: C -= Pn Pn^T over [k0+32,512)^2, tiles split across 16 blocks x 2 halves
      {
        const int T = 480 - k0;
        const int m = (T + 63) >> 6;
        const int P = m * (m + 1) / 2;
        const int h = t >> 8, tt = t & 255, ti = tt >> 4, tj = tt & 15;
        for (int tp = cb*2 + h; tp < P; tp += 2*CHOL_BLOCKS){
          int a = 0;
          while ((a + 1) * (a + 2) / 2 <= tp) a++;
          const int bb = tp - a * (a + 1) / 2;
          const int R  = k0 + 32 + a * 64;
          const int C0 = k0 + 32 + bb * 64;
          const int ra = R + ti * 4, ca = C0 + tj * 4;
          const int ral = ra > 508 ? 508 : ra;
          const int cal = ca > 508 ? 508 : ca;
          float acc[4][4];
          #pragma unroll
          for (int ii = 0; ii < 4; ++ii)
            #pragma unroll
            for (int jj = 0; jj < 4; ++jj) acc[ii][jj] = 0.f;
          #pragma unroll 4
          for (int c = 0; c < 32; ++c){
            float4 av = *(const float4*)&PnT[c][ral];
            float4 bv = *(const float4*)&PnT[c][cal];
            acc[0][0] += av.x*bv.x; acc[0][1] += av.x*bv.y; acc[0][2] += av.x*bv.z; acc[0][3] += av.x*bv.w;
            acc[1][0] += av.y*bv.x; acc[1][1] += av.y*bv.y; acc[1][2] += av.y*bv.z; acc[1][3] += av.y*bv.w;
            acc[2][0] += av.z*bv.x; acc[2][1] += av.z*bv.y; acc[2][2] += av.z*bv.z; acc[2][3] += av.z*bv.w;
            acc[3][0] += av.w*bv.x; acc[3][1] += av.w*bv.y; acc[3][2] += av.w*bv.z; acc[3][3] += av.w*bv.w;
          }
          if (ra < 512 && ca < 512){
            #pragma unroll
            for (int ii = 0; ii < 4; ++ii){
              const int r = ra + ii;
              float4 v = *(float4*)&M[r*512 + ca];
              v.x -= acc[ii][0]; v.y -= acc[ii][1]; v.z -= acc[ii][2]; v.w -= acc[ii][3];
              *(float4*)&M[r*512 + ca] = v;
            }
          }
        }
      }
      if (p < 15) gbarf(ws, cb, base + p + 1);   // SYRK visible before next panel stage
    }

    if (cb == 0){
      // -------- finale on chol block 0 (it finishes last; small path done ~130us earlier).
      // Small blocks increment WS_FIN fire-and-forget (no result dependency ->
      // no retirement serialization, the R5-R9 mega-fusion trap).
      if (t == 0){
        ws[WS_SCAL + 2] = 2.f * lgacc;
        int* cf = (int*)(ws + WS_FIN);
        while (__hip_atomic_load(cf, __ATOMIC_RELAXED, __HIP_MEMORY_SCOPE_AGENT) < SMALL_BLOCKS){
          __builtin_amdgcn_s_sleep(4);
        }
        (void)__hip_atomic_load(cf, __ATOMIC_ACQUIRE, __HIP_MEMORY_SCOPE_AGENT);  // S34 visible
        __hip_atomic_store(cf, 0, __ATOMIC_RELAXED, __HIP_MEMORY_SCOPE_AGENT);    // reset for replay
      }
      __syncthreads();
      float* red = smem;               // PnT dead; reuse LDS (verbatim k_final body)
      float v = 0.f;
      if (t < 500){
        const float* s = ws + WS_S34 + t*32;
        float mx = -1e30f;
        for (int a = 0; a < 32; ++a) mx = fmaxf(mx, s[a]);
        float sum = 0.f;
        for (int a = 0; a < 32; ++a) sum += expf(s[a] - mx);
        v = mx + logf(sum);
      }
      red[t] = v;
      __syncthreads();
      for (int s = 256; s; s >>= 1){ if (t < s) red[t] += red[t+s]; __syncthreads(); }
      if (t == 0){
        float step1 = ws[WS_SCAL+0];
        float step2 = ws[WS_SCAL+1];
        float ld    = ws[WS_SCAL+2];
        float step34 = red[0] - 500.f*ld;
        out[0] = -(step1 + step2 + step34);
      }
    }
  } else {
    // -------- 8 small 64x64 logdets + step4 per block, one per wave (R4 form) --------
    const int wid = threadIdx.x >> 6;            // 0..7
    const int t   = threadIdx.x & 63;            // lane
    const int sp  = ((int)blockIdx.x - CHOL_BLOCKS)*8 + wid;   // subproblem < 16000
    float4* pt   = reinterpret_cast<float4*>(smem) + (wid << 6);   // 64 float4 per wave
    float*  colb = smem + 2048 + (wid << 7);                       // 2x64 floats per wave (dbuf)
    const int idx = align[sp*64 + t];
    float4 own;
    own.x = mus[idx*3+0]; own.y = mus[idx*3+1]; own.z = mus[idx*3+2];
    own.w = ws[WS_Q + idx];
    pt[t] = own;
    wave_lds_sync();
    // build row t of sub = L[idx,idx] + jitter*I directly
    float x[64];
    #pragma unroll
    for (int j = 0; j < 64; ++j){
      float4 o = pt[j];
      float dx = own.x - o.x, dy = own.y - o.y, dz = own.z - o.z;
      float d2 = dx*dx + dy*dy + dz*dz;
      float v = own.w * o.w * expf(-0.5f*d2);
      if (j == t) v += 1e-6f;
      x[j] = v;
    }
    // Cholesky, row per lane. Pivot via SALU readlane (latency chain); column
    // broadcast via double-buffered LDS (throughput) -> one lgkm wait per column.
    float mydiag = 1.f;
    #pragma unroll
    for (int c = 0; c < 64; ++c){
      float piv = rdlane(x[c], c);
      float sq = sqrtf(fmaxf(piv, 1e-30f));
      float inv = 1.0f / sq;
      float xc = x[c] * inv;
      if (t == c){ xc = sq; mydiag = sq; }
      x[c] = xc;
      float* col = colb + ((c & 1) << 6);
      col[t] = (t > c) ? xc : 0.f;
      wave_lds_sync();                    // write visible; prev buffer's reads drained last iter
      const int j0 = c + 1;
      const int ja = (j0 + 3) & ~3;
      const int jh = (ja < 64) ? ja : 64;
      #pragma unroll
      for (int j = j0; j < jh; ++j) x[j] -= xc * col[j];
      #pragma unroll
      for (int j = ja; j < 64; j += 4){
        float4 cv = *(const float4*)&col[j];
        x[j+0] -= xc * cv.x;
        x[j+1] -= xc * cv.y;
        x[j+2] -= xc * cv.z;
        x[j+3] -= xc * cv.w;
      }
    }
    // per-lane: 2*log(diag) + step4 term for k = t
    const float* ch = ws + WS_CHR + ((sp >> 5)*64 + t)*3;
    float d0 = ch[0] - own.x, d1 = ch[1] - own.y, d2v = ch[2] - own.z;
    float v = 2.f*logf(mydiag) - 0.5f*(d0*d0 + d1*d1 + d2v*d2v);
    #pragma unroll
    for (int off = 32; off; off >>= 1) v += __shfl_down(v, off);
    if (t == 0) ws[WS_S34 + sp] = v - 96.f*LOG2PI_F;

    // block-completion: one fire-and-forget release increment per block.
    __syncthreads();
    if (threadIdx.x == 0){
      (void)__hip_atomic_fetch_add((int*)(ws + WS_FIN), 1,
                                   __ATOMIC_RELEASE, __HIP_MEMORY_SCOPE_AGENT);
    }
  }
}

extern "C" void kernel_launch(void* const* d_in, const int* in_sizes, int n_in,
                              void* d_out, int out_size, void* d_ws, size_t ws_size,
                              hipStream_t stream) {
  const float* colors = (const float*)d_in[0];
  const int*   align  = (const int*)  d_in[1];
  const float* mus    = (const float*)d_in[2];
  const float* fkw1   = (const float*)d_in[3];
  const float* fkb1   = (const float*)d_in[4];
  const float* fkw2   = (const float*)d_in[5];
  const float* fkb2   = (const float*)d_in[6];
  const float* dfw1   = (const float*)d_in[7];
  const float* dfb1   = (const float*)d_in[8];
  const float* dfw2   = (const float*)d_in[9];
  const float* dfb2   = (const float*)d_in[10];
  float* ws  = (float*)d_ws;
  float* out = (float*)d_out;

  hipLaunchKernelGGL(k_prep,  dim3(1),    dim3(512), 0, stream,
                     mus, fkw1, fkb1, fkw2, fkb2, dfw1, dfw2, ws);
  hipLaunchKernelGGL(k_cl,    dim3(1149), dim3(256), 0, stream, colors, dfb1, dfb2, mus, ws);
  hipLaunchKernelGGL(k_fused, dim3(SMALL_BLOCKS + CHOL_BLOCKS), dim3(512), 0, stream,
                     align, mus, ws, out);
}

// Round 13
// 327.206 us; speedup vs baseline: 1.0884x; 1.0884x over previous
//
#include <hip/hip_runtime.h>
#include <math.h>

#define LOG2PI_F 1.8378770664093453f

// ws layout (floats)
#define WS_Q    0                       // 512
#define WS_SCAL 512                     // 32: [2]=logdet_LI (only slot still used)
#define WS_M    544                     // 512*512 (L + I, consumed by big chol)
#define WS_CHR  (544 + 512*512)         // 500*64*3 = 96000
#define WS_S34  (WS_CHR + 96000)        // 16000
#define WS_FLG  (WS_S34 + 16000)        // 16 arrival flags, one per 128B line (16 x 32 ints)

#define CHOL_BLOCKS 16
#define SMALL_BLOCKS 2000

__device__ inline void inv3(const float* w, float* out){
  float a=w[0],b=w[1],c=w[2],d=w[3],e=w[4],f=w[5],g=w[6],h=w[7],i=w[8];
  float A = e*i - f*h;
  float B = -(d*i - f*g);
  float C = d*h - e*g;
  float det = a*A + b*B + c*C;
  float id = 1.0f/det;
  out[0]=A*id;            out[1]=-(b*i - c*h)*id; out[2]=(b*f - c*e)*id;
  out[3]=B*id;            out[4]=(a*i - c*g)*id;  out[5]=-(a*f - c*d)*id;
  out[6]=C*id;            out[7]=-(a*h - b*g)*id; out[8]=(a*e - b*d)*id;
}

// q(n) = exp(MLP(mus[n])) — identical expression/order to the old k_prep,
// so per-thread redundant evaluation is bit-identical.
__device__ inline float qval(const float* __restrict__ mus,
    const float* __restrict__ fkw1, const float* __restrict__ fkb1,
    const float* __restrict__ fkw2, const float* __restrict__ fkb2, int n){
  float m0 = mus[n*3+0], m1 = mus[n*3+1], m2 = mus[n*3+2];
  float h0 = tanhf(fkw1[0]*m0 + fkw1[1]*m1 + fkw1[2]*m2 + fkb1[0]);
  float h1 = tanhf(fkw1[3]*m0 + fkw1[4]*m1 + fkw1[5]*m2 + fkb1[1]);
  float h2 = tanhf(fkw1[6]*m0 + fkw1[7]*m1 + fkw1[8]*m2 + fkb1[2]);
  float logq = fkw2[0]*h0 + fkw2[1]*h1 + fkw2[2]*h2 + fkb2[0];
  return expf(logq);
}

// wave-local LDS ordering: a CDNA wave is lockstep, so draining the LDS queue
// is a sufficient barrier between lanes of the SAME wave.
__device__ inline void wave_lds_sync(){
  asm volatile("s_waitcnt lgkmcnt(0)" ::: "memory");
}

// broadcast lane l's value via SALU readlane (l compile-time constant in
// unrolled loops). ONLY on dependent pivot chains (latency-bound); the
// throughput-bound broadcast inner loops use LDS broadcast reads (R5 lesson).
__device__ inline float rdlane(float v, int l){
  return __int_as_float(__builtin_amdgcn_readlane(__float_as_int(v), l));
}

// Parallel arrival-flag device barrier (R11, measured ≈ atomic gbar): each
// block release-stores its own flag line; wave 0 polls all 16 with one vector
// load + __all. Monotonic base+round targets -> replay-robust.
__device__ inline void gbarf(float* ws, int cb, int target){
  __syncthreads();
  int* flags = (int*)(ws + WS_FLG);
  if (threadIdx.x == 0){
    __hip_atomic_store(&flags[cb*32], target, __ATOMIC_RELEASE, __HIP_MEMORY_SCOPE_AGENT);
  }
  if (threadIdx.x < 64){
    const int idx = (int)threadIdx.x & 15;      // 4 lanes per flag line
    for (;;){
      int v = __hip_atomic_load(&flags[idx*32], __ATOMIC_RELAXED, __HIP_MEMORY_SCOPE_AGENT);
      if (__all(v >= target)) break;
      __builtin_amdgcn_s_sleep(1);
    }
  }
  if (threadIdx.x == 0){
    (void)__hip_atomic_load(&flags[cb*32], __ATOMIC_ACQUIRE, __HIP_MEMORY_SCOPE_AGENT);
  }
  __syncthreads();
}

// ---------------- k_cl: chromes (blocks 0..124, inv3 inline) + build M = L+I
// (blocks 125..1148, q inline; blocks 125/126 publish WS_Q; block 0 zeroes flags).
// k_prep is GONE — all its outputs recomputed bit-identically at the consumer. ----------------
__global__ __launch_bounds__(256) void k_cl(const float* __restrict__ colors,
    const float* __restrict__ dfb1, const float* __restrict__ dfb2,
    const float* __restrict__ dfw1, const float* __restrict__ dfw2,
    const float* __restrict__ fkw1, const float* __restrict__ fkb1,
    const float* __restrict__ fkw2, const float* __restrict__ fkb2,
    const float* __restrict__ mus, float* ws){
  const int b = blockIdx.x;
  if (b < 125){
    if (b == 0){   // zero the 512-int flag region (visible to k_fused at launch boundary)
      ((int*)(ws + WS_FLG))[threadIdx.x]       = 0;
      ((int*)(ws + WS_FLG))[threadIdx.x + 256] = 0;
    }
    int id = b*256 + threadIdx.x;                 // < 32000 exact
    float w1i[9], w2i[9];
    inv3(dfw1, w1i);                              // same inputs -> same bits as k_prep
    inv3(dfw2, w2i);
    float c0 = colors[id*3+0] - dfb2[0];
    float c1 = colors[id*3+1] - dfb2[1];
    float c2 = colors[id*3+2] - dfb2[2];
    float z0 = w2i[0]*c0 + w2i[1]*c1 + w2i[2]*c2;
    float z1 = w2i[3]*c0 + w2i[4]*c1 + w2i[5]*c2;
    float z2 = w2i[6]*c0 + w2i[7]*c1 + w2i[8]*c2;
    const float lo = -1.0f + 1e-6f, hi = 1.0f - 1e-6f;
    z0 = atanhf(fminf(fmaxf(z0, lo), hi)) - dfb1[0];
    z1 = atanhf(fminf(fmaxf(z1, lo), hi)) - dfb1[1];
    z2 = atanhf(fminf(fmaxf(z2, lo), hi)) - dfb1[2];
    ws[WS_CHR + id*3+0] = w1i[0]*z0 + w1i[1]*z1 + w1i[2]*z2;
    ws[WS_CHR + id*3+1] = w1i[3]*z0 + w1i[4]*z1 + w1i[5]*z2;
    ws[WS_CHR + id*3+2] = w1i[6]*z0 + w1i[7]*z1 + w1i[8]*z2;
  } else {
    int id = (b - 125)*256 + threadIdx.x;         // < 262144 exact
    int i = id >> 9, j = id & 511;
    float qi = qval(mus, fkw1, fkb1, fkw2, fkb2, i);
    float qj = qval(mus, fkw1, fkb1, fkw2, fkb2, j);
    float dx = mus[i*3+0]-mus[j*3+0];
    float dy = mus[i*3+1]-mus[j*3+1];
    float dz = mus[i*3+2]-mus[j*3+2];
    float d2 = dx*dx + dy*dy + dz*dz;
    float v = qi*qj*expf(-0.5f*d2);
    if (i == j) v += 1.0f;
    ws[WS_M + id] = v;
    if (b < 127) ws[WS_Q + j] = qj;               // blocks 125,126 cover j = 0..511 exactly
  }
}

// ---------------- fused (R11 VERBATIM): blocks 0..15 = cooperative big Cholesky;
// blocks 16..2015 = 8 small 64x64 logdets each ----------------
__global__ __launch_bounds__(512) void k_fused(const int* __restrict__ align,
    const float* __restrict__ mus, float* ws){
  __shared__ __align__(16) float smem[16384];     // 64 KiB, overlaid by both paths

  if (blockIdx.x < CHOL_BLOCKS){
    // -------- big Cholesky on 16 workgroups (panel factor redundant, SYRK split 32 ways) --------
    __builtin_amdgcn_s_setprio(1);
    const int cb = blockIdx.x;
    float* M = ws + WS_M;
    float (*PnT)[512] = reinterpret_cast<float (*)[512]>(smem);   // [32][512]
    const int t = threadIdx.x;
    float lgacc = 0.f;
    // replay-robust barrier base: own flag's stale value (all flags equal at entry)
    const int base = __hip_atomic_load((int*)(ws + WS_FLG) + cb*32,
                                       __ATOMIC_RELAXED, __HIP_MEMORY_SCOPE_AGENT);

    for (int p = 0; p < 16; ++p){
      const int k0 = p << 5;
      const int H = 512 - k0;
      // stage panel cols [k0,k0+32) rows [k0,512) transposed into LDS
      if (t < H){
        const int r = k0 + t;
        #pragma unroll
        for (int c4 = 0; c4 < 8; ++c4){
          float4 v = *(const float4*)&M[r*512 + k0 + c4*4];
          PnT[c4*4+0][r] = v.x;
          PnT[c4*4+1][r] = v.y;
          PnT[c4*4+2][r] = v.z;
          PnT[c4*4+3][r] = v.w;
        }
      }
      __syncthreads();
      // diag-block Cholesky on wave 0 (lanes 0..31): SALU readlane broadcast
      if (t < 32){
        float x[32];
        #pragma unroll
        for (int c = 0; c < 32; ++c) x[c] = PnT[c][k0 + t];
        float invd = 1.f, mydiag = 1.f;
        #pragma unroll
        for (int c = 0; c < 32; ++c){
          float piv = rdlane(x[c], c);
          float sq = sqrtf(fmaxf(piv, 1e-30f));
          float inv = 1.0f / sq;
          float xc = x[c] * inv;
          if (t == c){ xc = sq; invd = inv; mydiag = sq; }
          x[c] = xc;
          #pragma unroll
          for (int j = c + 1; j < 32; ++j){
            float cj = rdlane(x[c], j);     // lane j's scaled column entry
            x[j] -= x[c] * cj;
          }
        }
        // write factor back transposed: zeros above diag, 1/Lcc on diag slot
        #pragma unroll
        for (int c = 0; c < 32; ++c){
          float val = (t > c) ? x[c] : ((t == c) ? invd : 0.f);
          PnT[c][k0 + t] = val;
        }
        float lg = logf(mydiag);
        #pragma unroll
        for (int off = 16; off; off >>= 1) lg += __shfl_down(lg, off);
        if (t == 0) lgacc += lg;
      }
      __syncthreads();
      // trsm (8 waves, one row/thread; R10 lesson: fewer waves exposes latency)
      {
        const int r = k0 + 32 + t;
        if (r < 512){
          float y[32];
          #pragma unroll
          for (int c = 0; c < 32; ++c) y[c] = PnT[c][r];
          #pragma unroll
          for (int c = 0; c < 32; ++c){
            const float inv = PnT[c][k0 + c];    // 1/Lcc
            const float yc = y[c] * inv;
            #pragma unroll
            for (int q4 = c >> 2; q4 < 8; ++q4){
              float4 f = *(const float4*)&PnT[c][k0 + q4*4];
              y[q4*4+0] -= yc * f.x;
              y[q4*4+1] -= yc * f.y;
              y[q4*4+2] -= yc * f.z;
              y[q4*4+3] -= yc * f.w;
            }
            y[c] = yc;   // fix slot clobbered by the diag-quad update
          }
          #pragma unroll
          for (int c = 0; c < 32; ++c) PnT[c][r] = y[c];
        }
      }
      __syncthreads();
      // trailing SYRK: C -= Pn Pn^T over [k0+32,512)^2, tiles split across 16 blocks x 2 halves
      {
        const int T = 480 - k0;
        const int m = (T + 63) >> 6;
        const int P = m * (m + 1) / 2;
        const int h = t >> 8, tt = t & 255, ti = tt >> 4, tj = tt & 15;
        for (int tp = cb*2 + h; tp < P; tp += 2*CHOL_BLOCKS){
          int a = 0;
          while ((a + 1) * (a + 2) / 2 <= tp) a++;
          const int bb = tp - a * (a + 1) / 2;
          const int R  = k0 + 32 + a * 64;
          const int C0 = k0 + 32 + bb * 64;
          const int ra = R + ti * 4, ca = C0 + tj * 4;
          const int ral = ra > 508 ? 508 : ra;
          const int cal = ca > 508 ? 508 : ca;
          float acc[4][4];
          #pragma unroll
          for (int ii = 0; ii < 4; ++ii)
            #pragma unroll
            for (int jj = 0; jj < 4; ++jj) acc[ii][jj] = 0.f;
          #pragma unroll 4
          for (int c = 0; c < 32; ++c){
            float4 av = *(const float4*)&PnT[c][ral];
            float4 bv = *(const float4*)&PnT[c][cal];
            acc[0][0] += av.x*bv.x; acc[0][1] += av.x*bv.y; acc[0][2] += av.x*bv.z; acc[0][3] += av.x*bv.w;
            acc[1][0] += av.y*bv.x; acc[1][1] += av.y*bv.y; acc[1][2] += av.y*bv.z; acc[1][3] += av.y*bv.w;
            acc[2][0] += av.z*bv.x; acc[2][1] += av.z*bv.y; acc[2][2] += av.z*bv.z; acc[2][3] += av.z*bv.w;
            acc[3][0] += av.w*bv.x; acc[3][1] += av.w*bv.y; acc[3][2] += av.w*bv.z; acc[3][3] += av.w*bv.w;
          }
          if (ra < 512 && ca < 512){
            #pragma unroll
            for (int ii = 0; ii < 4; ++ii){
              const int r = ra + ii;
              float4 v = *(float4*)&M[r*512 + ca];
              v.x -= acc[ii][0]; v.y -= acc[ii][1]; v.z -= acc[ii][2]; v.w -= acc[ii][3];
              *(float4*)&M[r*512 + ca] = v;
            }
          }
        }
      }
      if (p < 15) gbarf(ws, cb, base + p + 1);   // SYRK visible before next panel stage
    }
    if (cb == 0 && t == 0) ws[WS_SCAL + 2] = 2.f * lgacc;
  } else {
    // -------- 8 small 64x64 logdets + step4 per block, one per wave (R4 form) --------
    const int wid = threadIdx.x >> 6;            // 0..7
    const int t   = threadIdx.x & 63;            // lane
    const int sp  = ((int)blockIdx.x - CHOL_BLOCKS)*8 + wid;   // subproblem < 16000
    float4* pt   = reinterpret_cast<float4*>(smem) + (wid << 6);   // 64 float4 per wave
    float*  colb = smem + 2048 + (wid << 7);                       // 2x64 floats per wave (dbuf)
    const int idx = align[sp*64 + t];
    float4 own;
    own.x = mus[idx*3+0]; own.y = mus[idx*3+1]; own.z = mus[idx*3+2];
    own.w = ws[WS_Q + idx];
    pt[t] = own;
    wave_lds_sync();
    // build row t of sub = L[idx,idx] + jitter*I directly
    float x[64];
    #pragma unroll
    for (int j = 0; j < 64; ++j){
      float4 o = pt[j];
      float dx = own.x - o.x, dy = own.y - o.y, dz = own.z - o.z;
      float d2 = dx*dx + dy*dy + dz*dz;
      float v = own.w * o.w * expf(-0.5f*d2);
      if (j == t) v += 1e-6f;
      x[j] = v;
    }
    // Cholesky, row per lane. Pivot via SALU readlane (latency chain); column
    // broadcast via double-buffered LDS (throughput) -> one lgkm wait per column.
    float mydiag = 1.f;
    #pragma unroll
    for (int c = 0; c < 64; ++c){
      float piv = rdlane(x[c], c);
      float sq = sqrtf(fmaxf(piv, 1e-30f));
      float inv = 1.0f / sq;
      float xc = x[c] * inv;
      if (t == c){ xc = sq; mydiag = sq; }
      x[c] = xc;
      float* col = colb + ((c & 1) << 6);
      col[t] = (t > c) ? xc : 0.f;
      wave_lds_sync();                    // write visible; prev buffer's reads drained last iter
      const int j0 = c + 1;
      const int ja = (j0 + 3) & ~3;
      const int jh = (ja < 64) ? ja : 64;
      #pragma unroll
      for (int j = j0; j < jh; ++j) x[j] -= xc * col[j];
      #pragma unroll
      for (int j = ja; j < 64; j += 4){
        float4 cv = *(const float4*)&col[j];
        x[j+0] -= xc * cv.x;
        x[j+1] -= xc * cv.y;
        x[j+2] -= xc * cv.z;
        x[j+3] -= xc * cv.w;
      }
    }
    // per-lane: 2*log(diag) + step4 term for k = t
    const float* ch = ws + WS_CHR + ((sp >> 5)*64 + t)*3;
    float d0 = ch[0] - own.x, d1 = ch[1] - own.y, d2v = ch[2] - own.z;
    float v = 2.f*logf(mydiag) - 0.5f*(d0*d0 + d1*d1 + d2v*d2v);
    #pragma unroll
    for (int off = 32; off; off >>= 1) v += __shfl_down(v, off);
    if (t == 0) ws[WS_S34 + sp] = v - 96.f*LOG2PI_F;
  }
}

// ---------------- final: lse over A, sum over langs, step1+step2 inline, assemble ----------------
__global__ __launch_bounds__(512) void k_final(const float* __restrict__ ws,
    const float* __restrict__ mus, float* __restrict__ out){
  __shared__ float red[512];
  int t = threadIdx.x;
  float v = 0.f;
  if (t < 500){
    const float* s = ws + WS_S34 + t*32;
    float mx = -1e30f;
    for (int a = 0; a < 32; ++a) mx = fmaxf(mx, s[a]);
    float sum = 0.f;
    for (int a = 0; a < 32; ++a) sum += expf(s[a] - mx);
    v = mx + logf(sum);
  }
  red[t] = v;
  __syncthreads();
  for (int s = 256; s; s >>= 1){ if (t < s) red[t] += red[t+s]; __syncthreads(); }
  float slse = red[0];
  __syncthreads();
  // step2: identical tree pairing to the old k_prep (bit-exact)
  float m0 = mus[t*3+0], m1 = mus[t*3+1], m2 = mus[t*3+2];
  red[t] = -0.5f*(m0*m0 + m1*m1 + m2*m2);
  __syncthreads();
  for (int s = 256; s; s >>= 1){ if (t < s) red[t] += red[t+s]; __syncthreads(); }
  if (t == 0){
    float step2 = red[0] - 512.0f*1.5f*LOG2PI_F;
    float step1 = 512.0f*logf(500.0f) - 500.0f - lgammaf(513.0f);
    float ld    = ws[WS_SCAL+2];
    float step34 = slse - 500.f*ld;
    out[0] = -(step1 + step2 + step34);
  }
}

extern "C" void kernel_launch(void* const* d_in, const int* in_sizes, int n_in,
                              void* d_out, int out_size, void* d_ws, size_t ws_size,
                              hipStream_t stream) {
  const float* colors = (const float*)d_in[0];
  const int*   align  = (const int*)  d_in[1];
  const float* mus    = (const float*)d_in[2];
  const float* fkw1   = (const float*)d_in[3];
  const float* fkb1   = (const float*)d_in[4];
  const float* fkw2   = (const float*)d_in[5];
  const float* fkb2   = (const float*)d_in[6];
  const float* dfw1   = (const float*)d_in[7];
  const float* dfb1   = (const float*)d_in[8];
  const float* dfw2   = (const float*)d_in[9];
  const float* dfb2   = (const float*)d_in[10];
  float* ws  = (float*)d_ws;
  float* out = (float*)d_out;

  hipLaunchKernelGGL(k_cl,    dim3(1149), dim3(256), 0, stream,
                     colors, dfb1, dfb2, dfw1, dfw2, fkw1, fkb1, fkw2, fkb2, mus, ws);
  hipLaunchKernelGGL(k_fused, dim3(SMALL_BLOCKS + CHOL_BLOCKS), dim3(512), 0, stream,
                     align, mus, ws);
  hipLaunchKernelGGL(k_final, dim3(1),    dim3(512), 0, stream, ws, mus, out);
}